// Round 5
// baseline (222.446 us; speedup 1.0000x reference)
//
#include <hip/hip_runtime.h>
#include <hip/hip_bf16.h>

typedef __attribute__((ext_vector_type(8))) short bf16x8;
typedef __attribute__((ext_vector_type(4))) float f32x4;

// RNE float -> bf16 bits
static __device__ __forceinline__ ushort f2b(float f) {
    unsigned u = __float_as_uint(f);
    return (ushort)((u + 0x7fffu + ((u >> 16) & 1u)) >> 16);
}

static __device__ __forceinline__ void gload16(const void* g, void* lds) {
    __builtin_amdgcn_global_load_lds(
        (const __attribute__((address_space(1))) unsigned int*)g,
        (__attribute__((address_space(3))) unsigned int*)lds, 16, 0, 0);
}

// workspace layout (ws = 256 MiB)
#define MS ((size_t)8 << 20)            // one 64x256x256 bf16 matrix set
// idx: 0=xc 1=Y0 2=T0 3=Y1 4=T1 5=Y2 6=Z2 7=T2 8=Y3 9=Z3 10=T3 11=Y4 12=Z4 13=T4
#define TRI_OFF ((size_t)14 * MS)       // 112 MiB, 4,210,688 B
#define VAR_OFF ((size_t)122 << 20)     // 65,536 B
#define CNT_OFF (VAR_OFF + 65536)       // 256 B of counters
#define PART_OFF ((size_t)123 << 20)    // 128*64*384*4 = 12.58 MB

static __device__ __forceinline__ void sig_add(int* cb) {
    __hip_atomic_fetch_add(cb, 1, __ATOMIC_RELEASE, __HIP_MEMORY_SCOPE_AGENT);
}
static __device__ __forceinline__ void spin_until(int* cb, int tgt) {
    while (__hip_atomic_load(cb, __ATOMIC_RELAXED, __HIP_MEMORY_SCOPE_AGENT) < tgt)
        __builtin_amdgcn_s_sleep(1);
    (void)__hip_atomic_load(cb, __ATOMIC_ACQUIRE, __HIP_MEMORY_SCOPE_AGENT);
}

// stage a 128-row x 256-col bf16 panel (row stride 256) into tk-major [8][128][32]
static __device__ __forceinline__ void stage_panel(
    const ushort* __restrict__ rows, void* panel, int wv, int l)
{
    const int lrow = l >> 2;
    const int seg = (l & 3) * 8;
    #pragma unroll
    for (int it = 0; it < 16; ++it) {
        const int c = wv * 16 + it;            // chunk 0..63
        const int tk = c >> 3, r16 = c & 7;
        const int row = r16 * 16 + lrow;
        gload16(rows + (size_t)row * 256 + tk * 32 + seg,
                (char*)panel + tk * 8192 + r16 * 1024);
    }
}

static __device__ __forceinline__ void compute_tile(
    const ushort (&Ap)[8][128][32], const ushort (&Bp)[8][128][32],
    f32x4 (&acc)[4][4], int wr, int wc, int li, int hi)
{
    #pragma unroll
    for (int tk = 0; tk < 8; ++tk) {
        bf16x8 af[4], bfr[4];
        #pragma unroll
        for (int m = 0; m < 4; ++m)
            af[m] = *(const bf16x8*)&Ap[tk][wr * 64 + m * 16 + li][hi * 8];
        #pragma unroll
        for (int n = 0; n < 4; ++n)
            bfr[n] = *(const bf16x8*)&Bp[tk][wc * 64 + n * 16 + li][hi * 8];
        #pragma unroll
        for (int m = 0; m < 4; ++m)
            #pragma unroll
            for (int n = 0; n < 4; ++n)
                acc[m][n] = __builtin_amdgcn_mfma_f32_16x16x32_bf16(
                    af[m], bfr[n], acc[m][n], 0, 0, 0);
    }
}

#define ZERO_ACC do { _Pragma("unroll") for (int m = 0; m < 4; ++m) \
    _Pragma("unroll") for (int n = 0; n < 4; ++n) acc[m][n] = (f32x4){0.f,0.f,0.f,0.f}; } while (0)

// ---------------------------------------------------------------------------
// Persistent NS chain: 256 blocks (1/CU), 4 blocks per batch (tiles 2x2 of
// 128x128), per-batch atomic sync, whole-K(256)-resident LDS panels.
// ---------------------------------------------------------------------------
__global__ __launch_bounds__(256) void ns_chain(
    const float* __restrict__ x, char* __restrict__ ws)
{
    __shared__ ushort As[8][128][32];   // 64 KB
    __shared__ ushort Bs[8][128][32];   // 64 KB
    __shared__ float tr_s[4];

    const int blk = blockIdx.x;
    const int x8 = blk & 7, t = (blk >> 3) & 3, bhi = blk >> 5;
    const int b = bhi * 8 + x8;                    // XCD-pinned batch
    const int i0 = (t >> 1) * 128, j0 = (t & 1) * 128;
    const int tid = threadIdx.x, wv = tid >> 6, l = tid & 63;
    const int li = l & 15, hi = l >> 4, wr = wv >> 1, wc = wv & 1;
    const size_t bo = (size_t)b * 65536;

    ushort* xc = (ushort*)ws;
    float* var = (float*)(ws + VAR_OFF);
    int* cb = (int*)(ws + CNT_OFF) + b;
    ushort* tri = (ushort*)(ws + TRI_OFF);

    // ---- ph0: prep (mean-center my 64 rows, bf16, zero-pad K to 256) ----
    #pragma unroll 2
    for (int rr = 0; rr < 16; ++rr) {
        const int row = t * 64 + rr * 4 + wv;
        const float* xr = x + ((size_t)b * 256 + row) * 196;
        float x0 = xr[l], x1 = xr[l + 64], x2 = xr[l + 128];
        float x3 = (l < 4) ? xr[l + 192] : 0.0f;
        float s1 = x0 + x1 + x2 + x3;
        float s2 = x0 * x0 + x1 * x1 + x2 * x2 + x3 * x3;
        #pragma unroll
        for (int off = 32; off; off >>= 1) {
            s1 += __shfl_xor(s1, off);
            s2 += __shfl_xor(s2, off);
        }
        const float mean = s1 * (1.0f / 196.0f);
        if (l == 0) var[b * 256 + row] = s2 * (1.0f / 196.0f) - mean * mean + 1e-7f;
        ushort* xcr = xc + bo + (size_t)row * 256;
        xcr[l]       = f2b(x0 - mean);
        xcr[l + 64]  = f2b(x1 - mean);
        xcr[l + 128] = f2b(x2 - mean);
        xcr[l + 192] = (l < 4) ? f2b(x3 - mean) : (ushort)0;
    }
    __syncthreads();
    if (tid == 0) { sig_add(cb); spin_until(cb, 4); }
    __syncthreads();

    // ---- ph1: cov tile -> Y0, T0 (trace reduce folded under staging) ----
    stage_panel(xc + bo + (size_t)i0 * 256, As, wv, l);
    stage_panel(xc + bo + (size_t)j0 * 256, Bs, wv, l);
    {
        float v0 = var[b * 256 + tid];
        #pragma unroll
        for (int off = 32; off; off >>= 1) v0 += __shfl_xor(v0, off);
        if (l == 0) tr_s[wv] = v0;
    }
    __syncthreads();
    const float trace = tr_s[0] + tr_s[1] + tr_s[2] + tr_s[3];
    const float invtr = 1.0f / trace;

    f32x4 acc[4][4];
    ZERO_ACC;
    compute_tile(As, Bs, acc, wr, wc, li, hi);
    {
        ushort* Y0b = (ushort*)(ws + 1 * MS) + bo;
        ushort* T0b = (ushort*)(ws + 2 * MS) + bo;
        #pragma unroll
        for (int m = 0; m < 4; ++m)
        #pragma unroll
        for (int n = 0; n < 4; ++n)
        #pragma unroll
        for (int r = 0; r < 4; ++r) {
            const int gi = i0 + wr * 64 + m * 16 + hi * 4 + r;
            const int gj = j0 + wc * 64 + n * 16 + li;
            const float y0 = (acc[m][n][r] * (1.0f / 196.0f)
                              + ((gi == gj) ? 1e-7f : 0.0f)) * invtr;
            Y0b[(size_t)gi * 256 + gj] = f2b(y0);
            T0b[(size_t)gi * 256 + gj] = f2b(((gi == gj) ? 1.5f : 0.0f) - 0.5f * y0);
        }
    }
    __syncthreads();
    if (tid == 0) { sig_add(cb); spin_until(cb, 8); }
    __syncthreads();

    // ---- ph2: Y1 = Y0 * T0 ----
    stage_panel((ushort*)(ws + 1 * MS) + bo + (size_t)i0 * 256, As, wv, l);
    stage_panel((ushort*)(ws + 2 * MS) + bo + (size_t)j0 * 256, Bs, wv, l);
    __syncthreads();
    ZERO_ACC;
    compute_tile(As, Bs, acc, wr, wc, li, hi);
    {
        ushort* Y1b = (ushort*)(ws + 3 * MS) + bo;
        #pragma unroll
        for (int m = 0; m < 4; ++m)
        #pragma unroll
        for (int n = 0; n < 4; ++n)
        #pragma unroll
        for (int r = 0; r < 4; ++r) {
            const int gi = i0 + wr * 64 + m * 16 + hi * 4 + r;
            const int gj = j0 + wc * 64 + n * 16 + li;
            Y1b[(size_t)gi * 256 + gj] = f2b(acc[m][n][r]);
        }
    }
    // sync 3 — prestage Z1[i0] (= T0, old-stable) under the spin
    __syncthreads();
    if (tid == 0) sig_add(cb);
    stage_panel((ushort*)(ws + 2 * MS) + bo + (size_t)i0 * 256, As, wv, l);
    if (tid == 0) spin_until(cb, 12);
    __syncthreads();

    int tgt = 12;
    #pragma unroll 1
    for (int it = 0; it < 4; ++it) {
        const ushort* Zb = (const ushort*)(ws + (size_t)(it ? 3 * it + 3 : 2) * MS) + bo;
        const ushort* Yb = (const ushort*)(ws + (size_t)(it ? 3 * it + 2 : 3) * MS) + bo;
        ushort* Tb = (ushort*)(ws + (size_t)(3 * it + 4) * MS) + bo;

        // ---- T-phase: T = 1.5I - 0.5 * Z*Y  (tile i0,j0) ----
        if (it > 0) stage_panel(Zb + (size_t)i0 * 256, As, wv, l);  // it==0 prestaged
        stage_panel(Yb + (size_t)j0 * 256, Bs, wv, l);
        __syncthreads();
        ZERO_ACC;
        compute_tile(As, Bs, acc, wr, wc, li, hi);
        #pragma unroll
        for (int m = 0; m < 4; ++m)
        #pragma unroll
        for (int n = 0; n < 4; ++n)
        #pragma unroll
        for (int r = 0; r < 4; ++r) {
            const int gi = i0 + wr * 64 + m * 16 + hi * 4 + r;
            const int gj = j0 + wc * 64 + n * 16 + li;
            Tb[(size_t)gi * 256 + gj] =
                f2b(((gi == gj) ? 1.5f : 0.0f) - 0.5f * acc[m][n][r]);
        }
        // sync — prestage Y[i0] (old-stable) under the spin
        __syncthreads();
        if (tid == 0) sig_add(cb);
        stage_panel(Yb + (size_t)i0 * 256, As, wv, l);
        tgt += 4;
        if (tid == 0) spin_until(cb, tgt);
        __syncthreads();

        // ---- pair phase ----
        stage_panel(Tb + (size_t)j0 * 256, Bs, wv, l);   // fresh T[j0]
        __syncthreads();
        ZERO_ACC;
        compute_tile(As, Bs, acc, wr, wc, li, hi);       // Y' tile (i0,j0)
        if (it < 3) {
            ushort* Yob = (ushort*)(ws + (size_t)(3 * it + 5) * MS) + bo;
            #pragma unroll
            for (int m = 0; m < 4; ++m)
            #pragma unroll
            for (int n = 0; n < 4; ++n)
            #pragma unroll
            for (int r = 0; r < 4; ++r) {
                const int gi = i0 + wr * 64 + m * 16 + hi * 4 + r;
                const int gj = j0 + wc * 64 + n * 16 + li;
                Yob[(size_t)gi * 256 + gj] = f2b(acc[m][n][r]);
            }
            // Z' tile (j0,i0) = T[j0-rows] * Z[i0-rows]^T — reuse Bs(T), restage As(Z)
            __syncthreads();
            stage_panel(Zb + (size_t)i0 * 256, As, wv, l);
            __syncthreads();
            ZERO_ACC;
            compute_tile(Bs, As, acc, wr, wc, li, hi);
            ushort* Zob = (ushort*)(ws + (size_t)(3 * it + 6) * MS) + bo;
            #pragma unroll
            for (int m = 0; m < 4; ++m)
            #pragma unroll
            for (int n = 0; n < 4; ++n)
            #pragma unroll
            for (int r = 0; r < 4; ++r) {
                const int gi = j0 + wr * 64 + m * 16 + hi * 4 + r;
                const int gj = i0 + wc * 64 + n * 16 + li;
                Zob[(size_t)gi * 256 + gj] = f2b(acc[m][n][r]);
            }
            __syncthreads();
            if (tid == 0) sig_add(cb);
            tgt += 4;
            if (tid == 0) spin_until(cb, tgt);
            __syncthreads();
        } else if (t != 1) {
            // final: tri(Y5 * sqrt(trace)), lower tiles only (t=0,2,3)
            const float sc = sqrtf(trace);
            ushort* trib = tri + (size_t)b * 32896;
            #pragma unroll
            for (int m = 0; m < 4; ++m)
            #pragma unroll
            for (int n = 0; n < 4; ++n)
            #pragma unroll
            for (int r = 0; r < 4; ++r) {
                const int gi = i0 + wr * 64 + m * 16 + hi * 4 + r;
                const int gj = j0 + wc * 64 + n * 16 + li;
                if (gj <= gi)
                    trib[(gi * (gi + 1)) / 2 + gj] = f2b(acc[m][n][r] * sc);
            }
        }
    }
}

// ---------------------------------------------------------------------------
// FC: partial[split][64][384] = tri[64][K] * W[365][K]^T over this split's K
// 128 K-splits: 1028 = 4*9 + 124*8 steps of 32.
// ---------------------------------------------------------------------------
__global__ __launch_bounds__(256) void fc_gemm(
    const ushort* __restrict__ tri, const float* __restrict__ W,
    float* __restrict__ partial)
{
    __shared__ ushort As[64][40];
    __shared__ ushort Bs[64][40];

    const int ntile = blockIdx.x;              // 0..5
    const int split = blockIdx.y;              // 0..127
    const int steps = 8 + (split < 4 ? 1 : 0);
    const int step0 = split * 8 + (split < 4 ? split : 4);

    const int t   = threadIdx.x;
    const int row = t >> 2, seg = t & 3;
    const int wv  = t >> 6, l = t & 63;
    const int li  = l & 15, hi = l >> 4;
    const int n   = ntile * 64 + row;

    f32x4 acc[4];
    #pragma unroll
    for (int c = 0; c < 4; ++c) acc[c] = (f32x4){0.f, 0.f, 0.f, 0.f};

    for (int s = 0; s < steps; ++s) {
        const int kk = (step0 + s) * 32;
        *(bf16x8*)&As[row][seg * 8] =
            *(const bf16x8*)(tri + (size_t)row * 32896 + kk + seg * 8);
        bf16x8 pk;
        if (n < 365) {
            const float* wp = W + (size_t)n * 32896 + kk + seg * 8;
            float4 f0 = *(const float4*)wp;
            float4 f1 = *(const float4*)(wp + 4);
            pk[0] = (short)f2b(f0.x); pk[1] = (short)f2b(f0.y);
            pk[2] = (short)f2b(f0.z); pk[3] = (short)f2b(f0.w);
            pk[4] = (short)f2b(f1.x); pk[5] = (short)f2b(f1.y);
            pk[6] = (short)f2b(f1.z); pk[7] = (short)f2b(f1.w);
        } else {
            pk = (bf16x8){0,0,0,0,0,0,0,0};
        }
        *(bf16x8*)&Bs[row][seg * 8] = pk;
        __syncthreads();
        bf16x8 a = *(const bf16x8*)&As[wv * 16 + li][hi * 8];
        #pragma unroll
        for (int c = 0; c < 4; ++c) {
            bf16x8 bb = *(const bf16x8*)&Bs[c * 16 + li][hi * 8];
            acc[c] = __builtin_amdgcn_mfma_f32_16x16x32_bf16(a, bb, acc[c], 0, 0, 0);
        }
        __syncthreads();
    }

    #pragma unroll
    for (int c = 0; c < 4; ++c) {
        #pragma unroll
        for (int r = 0; r < 4; ++r) {
            const int i = wv * 16 + hi * 4 + r;          // batch
            const int j = ntile * 64 + c * 16 + li;      // class
            partial[((size_t)split * 64 + i) * 384 + j] = acc[c][r];
        }
    }
}

__global__ void fc_reduce(const float* __restrict__ partial,
                          const float* __restrict__ bias, float* __restrict__ out)
{
    const int idx = blockIdx.x * 256 + threadIdx.x;
    if (idx >= 64 * 365) return;
    const int b = idx / 365, n = idx % 365;
    float s = bias[n];
    #pragma unroll 4
    for (int sp = 0; sp < 128; ++sp)
        s += partial[((size_t)sp * 64 + b) * 384 + n];
    out[idx] = s;
}

// ---------------------------------------------------------------------------
extern "C" void kernel_launch(void* const* d_in, const int* in_sizes, int n_in,
                              void* d_out, int out_size, void* d_ws, size_t ws_size,
                              hipStream_t stream)
{
    (void)in_sizes; (void)n_in; (void)out_size; (void)ws_size;
    const float* x   = (const float*)d_in[0];
    const float* fcw = (const float*)d_in[1];
    const float* fcb = (const float*)d_in[2];
    float* out = (float*)d_out;
    char* ws = (char*)d_ws;

    hipMemsetAsync(ws + CNT_OFF, 0, 512, stream);
    ns_chain<<<256, 256, 0, stream>>>(x, ws);
    fc_gemm<<<dim3(6, 128), 256, 0, stream>>>(
        (const ushort*)(ws + TRI_OFF), fcw, (float*)(ws + PART_OFF));
    fc_reduce<<<(64 * 365 + 255) / 256, 256, 0, stream>>>(
        (const float*)(ws + PART_OFF), fcb, out);
}

// Round 6
// 136.929 us; speedup vs baseline: 1.6245x; 1.6245x over previous
//
#include <hip/hip_runtime.h>
#include <hip/hip_bf16.h>

typedef __attribute__((ext_vector_type(8))) short bf16x8;
typedef __attribute__((ext_vector_type(4))) float f32x4;

// RNE float -> bf16 bits
static __device__ __forceinline__ ushort f2b(float f) {
    unsigned u = __float_as_uint(f);
    return (ushort)((u + 0x7fffu + ((u >> 16) & 1u)) >> 16);
}

static __device__ __forceinline__ void gload16(const void* g, void* lds) {
    __builtin_amdgcn_global_load_lds(
        (const __attribute__((address_space(1))) unsigned int*)g,
        (__attribute__((address_space(3))) unsigned int*)lds, 16, 0, 0);
}

// ---------------------------------------------------------------------------
// prep: per (b,d) row of x[64][256][196]: mean-center, write bf16 into
// xc[64][256][256] (k=196..255 zero), var_d (+1e-7) per row for the trace.
// XCD-pinned: blockIdx%8 == batch%8.
// ---------------------------------------------------------------------------
__global__ __launch_bounds__(256) void prep_kernel(
    const float* __restrict__ x, ushort* __restrict__ xc, float* __restrict__ var)
{
    const int t = threadIdx.x, wv = t >> 6, l = t & 63;
    const int bid = blockIdx.x;
    const int x8 = bid & 7, rr = bid >> 3;
    const int dgrp = rr & 63, bgrp = rr >> 6;
    const int b = bgrp * 8 + x8;
    const int rowid = b * 256 + dgrp * 4 + wv;
    const float* xr = x + (size_t)rowid * 196;

    float x0 = xr[l];
    float x1 = xr[l + 64];
    float x2 = xr[l + 128];
    float x3 = (l < 4) ? xr[l + 192] : 0.0f;

    float s1 = x0 + x1 + x2 + x3;
    float s2 = x0*x0 + x1*x1 + x2*x2 + x3*x3;
    #pragma unroll
    for (int off = 32; off; off >>= 1) {
        s1 += __shfl_xor(s1, off);
        s2 += __shfl_xor(s2, off);
    }
    const float mean = s1 * (1.0f / 196.0f);
    if (l == 0) var[rowid] = s2 * (1.0f / 196.0f) - mean * mean + 1e-7f;

    ushort* xcr = xc + (size_t)rowid * 256;
    xcr[l]       = f2b(x0 - mean);
    xcr[l + 64]  = f2b(x1 - mean);
    xcr[l + 128] = f2b(x2 - mean);
    xcr[l + 192] = (l < 4) ? f2b(x3 - mean) : (ushort)0;   // zero pad 196..255
}

// ---------------------------------------------------------------------------
// Batched NT GEMM on symmetric operands. 128x128 tile, whole K=256 resident
// in LDS (tk-major [8][128][32] slabs), 4 waves (2x2, 64x64/wave),
// global_load_lds staging in two halves overlapped with compute.
// MODE 0: cov  : C = Y0 = (acc/196 + 1e-7 I)/trace[b];  C2 = 1.5I - 0.5*Y0
// MODE 1: T    : C = 1.5I - 0.5*acc
// MODE 2: pair : half grid: C = A*Bt^T; other half: C2 = A2*Bt^T
// MODE 3: tri  : lower-tri of acc*sqrt(trace[b]) -> C (3 tiles)
// MODE 4: plain: C = acc
// XCD-pinned: blockIdx%8 == batch%8 for every mode.
// ---------------------------------------------------------------------------
template<int H>
static __device__ __forceinline__ void stage_half(
    const ushort* Ab, const ushort* Btb, int i0, int j0,
    int wv, int lrow, int seg, ushort* As, ushort* Bs)
{
    #pragma unroll
    for (int it = 0; it < 8; ++it) {
        const int c = H * 32 + wv * 8 + it;       // chunk 0..63
        const int tk = c >> 3, r16 = c & 7;
        const int row = r16 * 16 + lrow;
        gload16(Ab + (size_t)(i0 + row) * 256 + tk * 32 + seg,
                (char*)As + tk * 8192 + r16 * 1024);
        gload16(Btb + (size_t)(j0 + row) * 256 + tk * 32 + seg,
                (char*)Bs + tk * 8192 + r16 * 1024);
    }
}

template<int MODE>
__global__ __launch_bounds__(256) void gemm_ns(
    const ushort* __restrict__ A, const ushort* __restrict__ A2,
    const ushort* __restrict__ Bt,
    ushort* __restrict__ C, ushort* __restrict__ C2,
    const float* __restrict__ var)
{
    __shared__ ushort As[8][128][32];   // 64 KB, tk-major slabs
    __shared__ ushort Bs[8][128][32];   // 64 KB
    __shared__ float tr_s[4];

    const int bid = blockIdx.x, x8 = bid & 7;
    int b, i0, j0;
    bool useA2 = false;
    if (MODE == 2) {
        const int tt = (bid >> 3) & 3;
        useA2 = ((bid >> 5) & 1) != 0;
        b = (bid >> 6) * 8 + x8;
        i0 = (tt >> 1) * 128; j0 = (tt & 1) * 128;
    } else if (MODE == 3) {
        const int rr = bid >> 3, t3 = rr % 3;
        b = (rr / 3) * 8 + x8;
        i0 = (t3 == 0) ? 0 : 128;
        j0 = (t3 == 2) ? 128 : 0;
    } else {
        const int tt = (bid >> 3) & 3;
        b = (bid >> 5) * 8 + x8;
        i0 = (tt >> 1) * 128; j0 = (tt & 1) * 128;
    }
    const ushort* Ab  = (useA2 ? A2 : A) + (size_t)b * 65536;
    const ushort* Btb = Bt + (size_t)b * 65536;

    const int t = threadIdx.x, wv = t >> 6, l = t & 63;
    const int li = l & 15, hi = l >> 4;
    const int wr = wv >> 1, wc = wv & 1;
    const int lrow = l >> 2;           // row within 16-row staging chunk
    const int seg = (l & 3) * 8;       // col offset in elements

    stage_half<0>(Ab, Btb, i0, j0, wv, lrow, seg, &As[0][0][0], &Bs[0][0][0]);

    // fold the per-batch trace reduction under the first staging wait
    if (MODE == 0 || MODE == 3) {
        float v = var[b * 256 + t];
        #pragma unroll
        for (int off = 32; off; off >>= 1) v += __shfl_xor(v, off);
        if (l == 0) tr_s[wv] = v;
    }
    __syncthreads();
    float trace = 0.f;
    if (MODE == 0 || MODE == 3) trace = tr_s[0] + tr_s[1] + tr_s[2] + tr_s[3];

    f32x4 acc[4][4];
    #pragma unroll
    for (int m = 0; m < 4; ++m)
        #pragma unroll
        for (int n = 0; n < 4; ++n) acc[m][n] = (f32x4){0.f, 0.f, 0.f, 0.f};

    stage_half<1>(Ab, Btb, i0, j0, wv, lrow, seg, &As[0][0][0], &Bs[0][0][0]);

    #pragma unroll
    for (int tk = 0; tk < 4; ++tk) {
        bf16x8 af[4], bfr[4];
        #pragma unroll
        for (int m = 0; m < 4; ++m)
            af[m] = *(const bf16x8*)&As[tk][wr * 64 + m * 16 + li][hi * 8];
        #pragma unroll
        for (int n = 0; n < 4; ++n)
            bfr[n] = *(const bf16x8*)&Bs[tk][wc * 64 + n * 16 + li][hi * 8];
        #pragma unroll
        for (int m = 0; m < 4; ++m)
            #pragma unroll
            for (int n = 0; n < 4; ++n)
                acc[m][n] = __builtin_amdgcn_mfma_f32_16x16x32_bf16(
                    af[m], bfr[n], acc[m][n], 0, 0, 0);
    }
    __syncthreads();
    #pragma unroll
    for (int tk = 4; tk < 8; ++tk) {
        bf16x8 af[4], bfr[4];
        #pragma unroll
        for (int m = 0; m < 4; ++m)
            af[m] = *(const bf16x8*)&As[tk][wr * 64 + m * 16 + li][hi * 8];
        #pragma unroll
        for (int n = 0; n < 4; ++n)
            bfr[n] = *(const bf16x8*)&Bs[tk][wc * 64 + n * 16 + li][hi * 8];
        #pragma unroll
        for (int m = 0; m < 4; ++m)
            #pragma unroll
            for (int n = 0; n < 4; ++n)
                acc[m][n] = __builtin_amdgcn_mfma_f32_16x16x32_bf16(
                    af[m], bfr[n], acc[m][n], 0, 0, 0);
    }

    if (MODE == 3) {
        const float sc = sqrtf(trace);
        ushort* trib = C + (size_t)b * 32896;
        #pragma unroll
        for (int m = 0; m < 4; ++m)
            #pragma unroll
            for (int n = 0; n < 4; ++n)
                #pragma unroll
                for (int r = 0; r < 4; ++r) {
                    const int gi = i0 + wr * 64 + m * 16 + hi * 4 + r;
                    const int gj = j0 + wc * 64 + n * 16 + li;
                    if (gj <= gi)
                        trib[(gi * (gi + 1)) / 2 + gj] = f2b(acc[m][n][r] * sc);
                }
    } else {
        const float invtr = (MODE == 0) ? (1.0f / trace) : 0.0f;
        ushort* Cb  = ((MODE == 2 && useA2) ? C2 : C) + (size_t)b * 65536;
        ushort* C2b = (MODE == 0) ? (C2 + (size_t)b * 65536) : nullptr;
        #pragma unroll
        for (int m = 0; m < 4; ++m)
            #pragma unroll
            for (int n = 0; n < 4; ++n)
                #pragma unroll
                for (int r = 0; r < 4; ++r) {
                    const int gi = i0 + wr * 64 + m * 16 + hi * 4 + r;
                    const int gj = j0 + wc * 64 + n * 16 + li;
                    const float v = acc[m][n][r];
                    const size_t idx = (size_t)gi * 256 + gj;
                    if (MODE == 0) {
                        float y0 = (v * (1.0f / 196.0f) + ((gi == gj) ? 1e-7f : 0.0f)) * invtr;
                        Cb[idx]  = f2b(y0);
                        C2b[idx] = f2b(((gi == gj) ? 1.5f : 0.0f) - 0.5f * y0);
                    } else if (MODE == 1) {
                        Cb[idx] = f2b(((gi == gj) ? 1.5f : 0.0f) - 0.5f * v);
                    } else {
                        Cb[idx] = f2b(v);
                    }
                }
    }
}

// ---------------------------------------------------------------------------
// FC: out[64][365] += tri[64][K] * W[365][K]^T  (fp32 atomics; out pre-zeroed;
// split-0 blocks add the bias). 128 K-splits: 1028 = 4*9 + 124*8 steps of 32.
// ---------------------------------------------------------------------------
__global__ __launch_bounds__(256) void fc_gemm(
    const ushort* __restrict__ tri, const float* __restrict__ W,
    const float* __restrict__ bias, float* __restrict__ out)
{
    __shared__ ushort As[64][40];
    __shared__ ushort Bs[64][40];

    const int ntile = blockIdx.x;              // 0..5
    const int split = blockIdx.y;              // 0..127
    const int steps = 8 + (split < 4 ? 1 : 0);
    const int step0 = split * 8 + (split < 4 ? split : 4);

    const int t   = threadIdx.x;
    const int row = t >> 2, seg = t & 3;
    const int wv  = t >> 6, l = t & 63;
    const int li  = l & 15, hi = l >> 4;
    const int n   = ntile * 64 + row;

    f32x4 acc[4];
    #pragma unroll
    for (int c = 0; c < 4; ++c) acc[c] = (f32x4){0.f, 0.f, 0.f, 0.f};

    for (int s = 0; s < steps; ++s) {
        const int kk = (step0 + s) * 32;
        *(bf16x8*)&As[row][seg * 8] =
            *(const bf16x8*)(tri + (size_t)row * 32896 + kk + seg * 8);
        bf16x8 pk;
        if (n < 365) {
            const float* wp = W + (size_t)n * 32896 + kk + seg * 8;
            float4 f0 = *(const float4*)wp;
            float4 f1 = *(const float4*)(wp + 4);
            pk[0] = (short)f2b(f0.x); pk[1] = (short)f2b(f0.y);
            pk[2] = (short)f2b(f0.z); pk[3] = (short)f2b(f0.w);
            pk[4] = (short)f2b(f1.x); pk[5] = (short)f2b(f1.y);
            pk[6] = (short)f2b(f1.z); pk[7] = (short)f2b(f1.w);
        } else {
            pk = (bf16x8){0,0,0,0,0,0,0,0};
        }
        *(bf16x8*)&Bs[row][seg * 8] = pk;
        __syncthreads();
        bf16x8 a = *(const bf16x8*)&As[wv * 16 + li][hi * 8];
        #pragma unroll
        for (int c = 0; c < 4; ++c) {
            bf16x8 bb = *(const bf16x8*)&Bs[c * 16 + li][hi * 8];
            acc[c] = __builtin_amdgcn_mfma_f32_16x16x32_bf16(a, bb, acc[c], 0, 0, 0);
        }
        __syncthreads();
    }

    #pragma unroll
    for (int c = 0; c < 4; ++c) {
        #pragma unroll
        for (int r = 0; r < 4; ++r) {
            const int i = wv * 16 + hi * 4 + r;          // batch
            const int j = ntile * 64 + c * 16 + li;      // class
            if (j < 365) {
                float v = acc[c][r];
                if (split == 0) v += bias[j];
                atomicAdd(&out[(size_t)i * 365 + j], v);
            }
        }
    }
}

// ---------------------------------------------------------------------------
extern "C" void kernel_launch(void* const* d_in, const int* in_sizes, int n_in,
                              void* d_out, int out_size, void* d_ws, size_t ws_size,
                              hipStream_t stream)
{
    (void)in_sizes; (void)n_in; (void)ws_size;
    const float* x   = (const float*)d_in[0];
    const float* fcw = (const float*)d_in[1];
    const float* fcb = (const float*)d_in[2];
    float* out = (float*)d_out;
    char* ws = (char*)d_ws;

    const size_t MS = (size_t)64 * 256 * 256 * 2;   // 8 MiB per matrix buffer
    ushort* w0 = (ushort*)(ws + 0 * MS);
    ushort* w1 = (ushort*)(ws + 1 * MS);
    ushort* w2 = (ushort*)(ws + 2 * MS);
    ushort* w3 = (ushort*)(ws + 3 * MS);
    ushort* w4 = (ushort*)(ws + 4 * MS);
    ushort* xc = (ushort*)(ws + 5 * MS);                     // 8 MiB (padded K=256)
    float*  var    = (float*)(ws + 6 * MS);                  // 65,536 B
    ushort* tri    = (ushort*)(ws + 6 * MS + 131072);        // 4,210,688 B

    hipMemsetAsync(out, 0, (size_t)out_size * sizeof(float), stream);
    prep_kernel<<<4096, 256, 0, stream>>>(x, xc, var);

    // cov: Y0 -> w0, T0 -> w1
    gemm_ns<0><<<256, 256, 0, stream>>>(xc, nullptr, xc, w0, w1, var);
    // Y1 = Y0*T0 -> w2   (Z1 = T0 = w1)
    gemm_ns<4><<<256, 256, 0, stream>>>(w0, nullptr, w1, w2, nullptr, nullptr);
    // iter2 (Y=w2, Z=w1): T -> w0 ; Y' -> w3 ; Z' -> w4
    gemm_ns<1><<<256, 256, 0, stream>>>(w1, nullptr, w2, w0, nullptr, nullptr);
    gemm_ns<2><<<512, 256, 0, stream>>>(w2, w1, w0, w3, w4, nullptr);
    // iter3 (Y=w3, Z=w4): T -> w0 ; Y' -> w1 ; Z' -> w2
    gemm_ns<1><<<256, 256, 0, stream>>>(w4, nullptr, w3, w0, nullptr, nullptr);
    gemm_ns<2><<<512, 256, 0, stream>>>(w3, w4, w0, w1, w2, nullptr);
    // iter4 (Y=w1, Z=w2): T -> w0 ; Y' -> w3 ; Z' -> w4
    gemm_ns<1><<<256, 256, 0, stream>>>(w2, nullptr, w1, w0, nullptr, nullptr);
    gemm_ns<2><<<512, 256, 0, stream>>>(w1, w2, w0, w3, w4, nullptr);
    // iter5 (Y=w3, Z=w4): T -> w0 ; tri(Y*T*sqrt(trace)) -> tri
    gemm_ns<1><<<256, 256, 0, stream>>>(w4, nullptr, w3, w0, nullptr, nullptr);
    gemm_ns<3><<<192, 256, 0, stream>>>(w3, nullptr, w0, tri, nullptr, var);

    fc_gemm<<<dim3(6, 128), 256, 0, stream>>>(tri, fcw, fcb, out);
}

// Round 7
// 122.823 us; speedup vs baseline: 1.8111x; 1.1148x over previous
//
#include <hip/hip_runtime.h>
#include <hip/hip_bf16.h>

typedef __attribute__((ext_vector_type(8))) short bf16x8;
typedef __attribute__((ext_vector_type(4))) float f32x4;

// RNE float -> bf16 bits
static __device__ __forceinline__ ushort f2b(float f) {
    unsigned u = __float_as_uint(f);
    return (ushort)((u + 0x7fffu + ((u >> 16) & 1u)) >> 16);
}

static __device__ __forceinline__ void gload16(const void* g, void* lds) {
    __builtin_amdgcn_global_load_lds(
        (const __attribute__((address_space(1))) unsigned int*)g,
        (__attribute__((address_space(3))) unsigned int*)lds, 16, 0, 0);
}

// ---------------------------------------------------------------------------
// prep: per (b,d) row of x[64][256][196]: mean-center, write bf16 into
// xc[64][256][256] (k=196..255 zero), var_d (+1e-7) per row for the trace.
// XCD-pinned: blockIdx%8 == batch%8.
// ---------------------------------------------------------------------------
__global__ __launch_bounds__(256) void prep_kernel(
    const float* __restrict__ x, ushort* __restrict__ xc, float* __restrict__ var)
{
    const int t = threadIdx.x, wv = t >> 6, l = t & 63;
    const int bid = blockIdx.x;
    const int x8 = bid & 7, rr = bid >> 3;
    const int dgrp = rr & 63, bgrp = rr >> 6;
    const int b = bgrp * 8 + x8;
    const int rowid = b * 256 + dgrp * 4 + wv;
    const float* xr = x + (size_t)rowid * 196;

    float x0 = xr[l];
    float x1 = xr[l + 64];
    float x2 = xr[l + 128];
    float x3 = (l < 4) ? xr[l + 192] : 0.0f;

    float s1 = x0 + x1 + x2 + x3;
    float s2 = x0*x0 + x1*x1 + x2*x2 + x3*x3;
    #pragma unroll
    for (int off = 32; off; off >>= 1) {
        s1 += __shfl_xor(s1, off);
        s2 += __shfl_xor(s2, off);
    }
    const float mean = s1 * (1.0f / 196.0f);
    if (l == 0) var[rowid] = s2 * (1.0f / 196.0f) - mean * mean + 1e-7f;

    ushort* xcr = xc + (size_t)rowid * 256;
    xcr[l]       = f2b(x0 - mean);
    xcr[l + 64]  = f2b(x1 - mean);
    xcr[l + 128] = f2b(x2 - mean);
    xcr[l + 192] = (l < 4) ? f2b(x3 - mean) : (ushort)0;   // zero pad 196..255
}

// ---------------------------------------------------------------------------
// Batched NT GEMM on symmetric operands. 128x128 tile, whole K=256 resident
// in LDS (tk-major [8][128][32] slabs), 4 waves (2x2, 64x64/wave),
// global_load_lds staging in two halves overlapped with compute.
// MODE 0: cov  : C = Y0 = (acc/196 + 1e-7 I)/trace[b];  C2 = 1.5I - 0.5*Y0
// MODE 1: T    : C = 1.5I - 0.5*acc
// MODE 2: pair : half grid: C = A*Bt^T; other half: C2 = A2*Bt^T
// MODE 3: tri  : lower-tri of acc*sqrt(trace[b]) -> C (3 tiles)
// MODE 4: plain: C = acc
// XCD-pinned: blockIdx%8 == batch%8 for every mode.
// ---------------------------------------------------------------------------
template<int H>
static __device__ __forceinline__ void stage_half(
    const ushort* Ab, const ushort* Btb, int i0, int j0,
    int wv, int lrow, int seg, ushort* As, ushort* Bs)
{
    #pragma unroll
    for (int it = 0; it < 8; ++it) {
        const int c = H * 32 + wv * 8 + it;       // chunk 0..63
        const int tk = c >> 3, r16 = c & 7;
        const int row = r16 * 16 + lrow;
        gload16(Ab + (size_t)(i0 + row) * 256 + tk * 32 + seg,
                (char*)As + tk * 8192 + r16 * 1024);
        gload16(Btb + (size_t)(j0 + row) * 256 + tk * 32 + seg,
                (char*)Bs + tk * 8192 + r16 * 1024);
    }
}

template<int MODE>
__global__ __launch_bounds__(256) void gemm_ns(
    const ushort* __restrict__ A, const ushort* __restrict__ A2,
    const ushort* __restrict__ Bt,
    ushort* __restrict__ C, ushort* __restrict__ C2,
    const float* __restrict__ var)
{
    __shared__ ushort As[8][128][32];   // 64 KB, tk-major slabs
    __shared__ ushort Bs[8][128][32];   // 64 KB
    __shared__ float tr_s[4];

    const int bid = blockIdx.x, x8 = bid & 7;
    int b, i0, j0;
    bool useA2 = false;
    if (MODE == 2) {
        const int tt = (bid >> 3) & 3;
        useA2 = ((bid >> 5) & 1) != 0;
        b = (bid >> 6) * 8 + x8;
        i0 = (tt >> 1) * 128; j0 = (tt & 1) * 128;
    } else if (MODE == 3) {
        const int rr = bid >> 3, t3 = rr % 3;
        b = (rr / 3) * 8 + x8;
        i0 = (t3 == 0) ? 0 : 128;
        j0 = (t3 == 2) ? 128 : 0;
    } else {
        const int tt = (bid >> 3) & 3;
        b = (bid >> 5) * 8 + x8;
        i0 = (tt >> 1) * 128; j0 = (tt & 1) * 128;
    }
    const ushort* Ab  = (useA2 ? A2 : A) + (size_t)b * 65536;
    const ushort* Btb = Bt + (size_t)b * 65536;

    const int t = threadIdx.x, wv = t >> 6, l = t & 63;
    const int li = l & 15, hi = l >> 4;
    const int wr = wv >> 1, wc = wv & 1;
    const int lrow = l >> 2;           // row within 16-row staging chunk
    const int seg = (l & 3) * 8;       // col offset in elements

    stage_half<0>(Ab, Btb, i0, j0, wv, lrow, seg, &As[0][0][0], &Bs[0][0][0]);

    // fold the per-batch trace reduction under the first staging wait
    if (MODE == 0 || MODE == 3) {
        float v = var[b * 256 + t];
        #pragma unroll
        for (int off = 32; off; off >>= 1) v += __shfl_xor(v, off);
        if (l == 0) tr_s[wv] = v;
    }
    __syncthreads();
    float trace = 0.f;
    if (MODE == 0 || MODE == 3) trace = tr_s[0] + tr_s[1] + tr_s[2] + tr_s[3];

    f32x4 acc[4][4];
    #pragma unroll
    for (int m = 0; m < 4; ++m)
        #pragma unroll
        for (int n = 0; n < 4; ++n) acc[m][n] = (f32x4){0.f, 0.f, 0.f, 0.f};

    stage_half<1>(Ab, Btb, i0, j0, wv, lrow, seg, &As[0][0][0], &Bs[0][0][0]);

    #pragma unroll
    for (int tk = 0; tk < 4; ++tk) {
        bf16x8 af[4], bfr[4];
        #pragma unroll
        for (int m = 0; m < 4; ++m)
            af[m] = *(const bf16x8*)&As[tk][wr * 64 + m * 16 + li][hi * 8];
        #pragma unroll
        for (int n = 0; n < 4; ++n)
            bfr[n] = *(const bf16x8*)&Bs[tk][wc * 64 + n * 16 + li][hi * 8];
        #pragma unroll
        for (int m = 0; m < 4; ++m)
            #pragma unroll
            for (int n = 0; n < 4; ++n)
                acc[m][n] = __builtin_amdgcn_mfma_f32_16x16x32_bf16(
                    af[m], bfr[n], acc[m][n], 0, 0, 0);
    }
    __syncthreads();
    #pragma unroll
    for (int tk = 4; tk < 8; ++tk) {
        bf16x8 af[4], bfr[4];
        #pragma unroll
        for (int m = 0; m < 4; ++m)
            af[m] = *(const bf16x8*)&As[tk][wr * 64 + m * 16 + li][hi * 8];
        #pragma unroll
        for (int n = 0; n < 4; ++n)
            bfr[n] = *(const bf16x8*)&Bs[tk][wc * 64 + n * 16 + li][hi * 8];
        #pragma unroll
        for (int m = 0; m < 4; ++m)
            #pragma unroll
            for (int n = 0; n < 4; ++n)
                acc[m][n] = __builtin_amdgcn_mfma_f32_16x16x32_bf16(
                    af[m], bfr[n], acc[m][n], 0, 0, 0);
    }

    if (MODE == 3) {
        const float sc = sqrtf(trace);
        ushort* trib = C + (size_t)b * 32896;
        #pragma unroll
        for (int m = 0; m < 4; ++m)
            #pragma unroll
            for (int n = 0; n < 4; ++n)
                #pragma unroll
                for (int r = 0; r < 4; ++r) {
                    const int gi = i0 + wr * 64 + m * 16 + hi * 4 + r;
                    const int gj = j0 + wc * 64 + n * 16 + li;
                    if (gj <= gi)
                        trib[(gi * (gi + 1)) / 2 + gj] = f2b(acc[m][n][r] * sc);
                }
    } else {
        const float invtr = (MODE == 0) ? (1.0f / trace) : 0.0f;
        ushort* Cb  = ((MODE == 2 && useA2) ? C2 : C) + (size_t)b * 65536;
        ushort* C2b = (MODE == 0) ? (C2 + (size_t)b * 65536) : nullptr;
        #pragma unroll
        for (int m = 0; m < 4; ++m)
            #pragma unroll
            for (int n = 0; n < 4; ++n)
                #pragma unroll
                for (int r = 0; r < 4; ++r) {
                    const int gi = i0 + wr * 64 + m * 16 + hi * 4 + r;
                    const int gj = j0 + wc * 64 + n * 16 + li;
                    const float v = acc[m][n][r];
                    const size_t idx = (size_t)gi * 256 + gj;
                    if (MODE == 0) {
                        float y0 = (v * (1.0f / 196.0f) + ((gi == gj) ? 1e-7f : 0.0f)) * invtr;
                        Cb[idx]  = f2b(y0);
                        C2b[idx] = f2b(((gi == gj) ? 1.5f : 0.0f) - 0.5f * y0);
                    } else if (MODE == 1) {
                        Cb[idx] = f2b(((gi == gj) ? 1.5f : 0.0f) - 0.5f * v);
                    } else {
                        Cb[idx] = f2b(v);
                    }
                }
    }
}

// ---------------------------------------------------------------------------
// FC: partial[split][64][384] = tri[64][K] * W[365][K]^T over this split's K.
// Counted-vmcnt streaming pipeline: 4-deep ring of per-step LDS slabs
// (A: 64x32 bf16 = 4KB via 1 gload16/thread; W: 64x32 fp32 = 8KB via 2),
// 3 steps in flight (vmcnt(9)), raw s_barrier, W converted on LDS read.
// 64 K-splits: 1028 steps of 32 = 4*17 + 60*16.
// ---------------------------------------------------------------------------
__global__ __launch_bounds__(256) void fc_gemm(
    const ushort* __restrict__ tri, const float* __restrict__ W,
    float* __restrict__ partial)
{
    __shared__ ushort Asl[4][64][32];   // 16 KB
    __shared__ float  Wsl[4][64][32];   // 32 KB

    const int ntile = blockIdx.x;              // 0..5
    const int split = blockIdx.y;              // 0..63
    const int steps = 16 + (split < 4 ? 1 : 0);
    const int step0 = split * 16 + (split < 4 ? split : 4);

    const int tid = threadIdx.x, wv = tid >> 6, l = tid & 63;
    const int li = l & 15, hi = l >> 4;

    // staging geometry (dest is lane-linear per wave by construction)
    const int arow = tid >> 2, aseg = tid & 3;            // A: 1 granule/thread
    const int wrow0 = tid >> 3, wseg = tid & 7;           // W: 2 granules/thread
    const int wrow1 = 32 + (tid >> 3);
    const int wcl0 = min(ntile * 64 + wrow0, 364);
    const int wcl1 = min(ntile * 64 + wrow1, 364);

#define FSTAGE(s) do {                                                          \
    const int kk_ = (step0 + (s)) * 32;                                         \
    const int r_ = (s) & 3;                                                     \
    gload16(tri + (size_t)arow * 32896 + kk_ + aseg * 8,                        \
            &Asl[r_][arow][aseg * 8]);                                          \
    gload16(W + (size_t)wcl0 * 32896 + kk_ + wseg * 4,                          \
            &Wsl[r_][wrow0][wseg * 4]);                                         \
    gload16(W + (size_t)wcl1 * 32896 + kk_ + wseg * 4,                          \
            &Wsl[r_][wrow1][wseg * 4]);                                         \
} while (0)

    FSTAGE(0); FSTAGE(1); FSTAGE(2);

    f32x4 acc[4];
    #pragma unroll
    for (int m = 0; m < 4; ++m) acc[m] = (f32x4){0.f, 0.f, 0.f, 0.f};

    for (int s = 0; s < steps; ++s) {
        if (s + 3 < steps) FSTAGE(s + 3);
        asm volatile("s_waitcnt vmcnt(9)" ::: "memory");
        __builtin_amdgcn_sched_barrier(0);
        __builtin_amdgcn_s_barrier();

        const int r = s & 3;
        const float4 wf0 = *(const float4*)&Wsl[r][wv * 16 + li][hi * 8];
        const float4 wf1 = *(const float4*)&Wsl[r][wv * 16 + li][hi * 8 + 4];
        bf16x8 bfr;
        bfr[0] = (short)f2b(wf0.x); bfr[1] = (short)f2b(wf0.y);
        bfr[2] = (short)f2b(wf0.z); bfr[3] = (short)f2b(wf0.w);
        bfr[4] = (short)f2b(wf1.x); bfr[5] = (short)f2b(wf1.y);
        bfr[6] = (short)f2b(wf1.z); bfr[7] = (short)f2b(wf1.w);

        bf16x8 af[4];
        #pragma unroll
        for (int m = 0; m < 4; ++m)
            af[m] = *(const bf16x8*)&Asl[r][m * 16 + li][hi * 8];
        #pragma unroll
        for (int m = 0; m < 4; ++m)
            acc[m] = __builtin_amdgcn_mfma_f32_16x16x32_bf16(af[m], bfr, acc[m], 0, 0, 0);

        __builtin_amdgcn_s_barrier();
    }
#undef FSTAGE

    #pragma unroll
    for (int m = 0; m < 4; ++m)
        #pragma unroll
        for (int rr = 0; rr < 4; ++rr) {
            const int i = m * 16 + hi * 4 + rr;          // batch
            const int j = ntile * 64 + wv * 16 + li;     // class (<384)
            partial[((size_t)split * 64 + i) * 384 + j] = acc[m][rr];
        }
}

__global__ void fc_reduce(const float* __restrict__ partial,
                          const float* __restrict__ bias, float* __restrict__ out)
{
    const int idx = blockIdx.x * 256 + threadIdx.x;
    if (idx >= 64 * 365) return;
    const int b = idx / 365, n = idx % 365;
    float s = bias[n];
    #pragma unroll 4
    for (int sp = 0; sp < 64; ++sp)
        s += partial[((size_t)sp * 64 + b) * 384 + n];
    out[idx] = s;
}

// ---------------------------------------------------------------------------
extern "C" void kernel_launch(void* const* d_in, const int* in_sizes, int n_in,
                              void* d_out, int out_size, void* d_ws, size_t ws_size,
                              hipStream_t stream)
{
    (void)in_sizes; (void)n_in; (void)out_size; (void)ws_size;
    const float* x   = (const float*)d_in[0];
    const float* fcw = (const float*)d_in[1];
    const float* fcb = (const float*)d_in[2];
    float* out = (float*)d_out;
    char* ws = (char*)d_ws;

    const size_t MS = (size_t)64 * 256 * 256 * 2;   // 8 MiB per matrix buffer
    ushort* w0 = (ushort*)(ws + 0 * MS);
    ushort* w1 = (ushort*)(ws + 1 * MS);
    ushort* w2 = (ushort*)(ws + 2 * MS);
    ushort* w3 = (ushort*)(ws + 3 * MS);
    ushort* w4 = (ushort*)(ws + 4 * MS);
    ushort* xc = (ushort*)(ws + 5 * MS);                     // 8 MiB (padded K=256)
    float*  var    = (float*)(ws + 6 * MS);                  // 65,536 B
    ushort* tri    = (ushort*)(ws + 6 * MS + 131072);        // 4,210,688 B
    float*  partial= (float*)(ws + 6 * MS + 131072 + 4210688);  // 6.3 MB

    prep_kernel<<<4096, 256, 0, stream>>>(x, xc, var);

    // cov: Y0 -> w0, T0 -> w1
    gemm_ns<0><<<256, 256, 0, stream>>>(xc, nullptr, xc, w0, w1, var);
    // Y1 = Y0*T0 -> w2   (Z1 = T0 = w1)
    gemm_ns<4><<<256, 256, 0, stream>>>(w0, nullptr, w1, w2, nullptr, nullptr);
    // iter2 (Y=w2, Z=w1): T -> w0 ; Y' -> w3 ; Z' -> w4
    gemm_ns<1><<<256, 256, 0, stream>>>(w1, nullptr, w2, w0, nullptr, nullptr);
    gemm_ns<2><<<512, 256, 0, stream>>>(w2, w1, w0, w3, w4, nullptr);
    // iter3 (Y=w3, Z=w4): T -> w0 ; Y' -> w1 ; Z' -> w2
    gemm_ns<1><<<256, 256, 0, stream>>>(w4, nullptr, w3, w0, nullptr, nullptr);
    gemm_ns<2><<<512, 256, 0, stream>>>(w3, w4, w0, w1, w2, nullptr);
    // iter4 (Y=w1, Z=w2): T -> w0 ; Y' -> w3 ; Z' -> w4
    gemm_ns<1><<<256, 256, 0, stream>>>(w2, nullptr, w1, w0, nullptr, nullptr);
    gemm_ns<2><<<512, 256, 0, stream>>>(w1, w2, w0, w3, w4, nullptr);
    // iter5 (Y=w3, Z=w4): T -> w0 ; tri(Y*T*sqrt(trace)) -> tri
    gemm_ns<1><<<256, 256, 0, stream>>>(w4, nullptr, w3, w0, nullptr, nullptr);
    gemm_ns<3><<<192, 256, 0, stream>>>(w3, nullptr, w0, tri, nullptr, var);

    fc_gemm<<<dim3(6, 64), 256, 0, stream>>>(tri, fcw, partial);
    fc_reduce<<<(64 * 365 + 255) / 256, 256, 0, stream>>>(partial, fcb, out);
}